// Round 19
// baseline (3793.734 us; speedup 1.0000x reference)
//
#include <hip/hip_runtime.h>
#include <math.h>
#include <stdint.h>

typedef float f32x4 __attribute__((ext_vector_type(4)));

__device__ __forceinline__ float sigm(float x) { return 1.0f/(1.0f+expf(-x)); }

// Sum across each 8-lane group via DIRECTION-PROOF DPP involutions (round-16
// lesson: ror over sub-groups is direction-sensitive; xor/mirror are not).
__device__ __forceinline__ float red8(float v) {
    int t;
    t = __builtin_amdgcn_update_dpp(0, __float_as_int(v), 0xB1, 0xf, 0xf, false);
    v += __int_as_float(t);   // + lane^1
    t = __builtin_amdgcn_update_dpp(0, __float_as_int(v), 0x4E, 0xf, 0xf, false);
    v += __int_as_float(t);   // + lane^2 -> quad sums
    t = __builtin_amdgcn_update_dpp(0, __float_as_int(v), 0x141, 0xf, 0xf, false);
    v += __int_as_float(t);   // + row_half_mirror -> 8-sum in all lanes
    return v;
}

// ------------- Kernel 1: LSTM recurrence, partially-resident W -------------
// Round-18 analysis: 10.6us/step = VALU 5.0 + aggregate-L2 floor 7.4 (256 CU
// x 1MiB/step / 34.5TB/s), imperfectly overlapped. Pipeline tweaks can't get
// below the L2 floor -- only cutting traffic can. This round: 6/16 of W made
// CU-resident. Phases 12-15 in REGISTERS (16 named f32x4/lane = 64 VGPR;
// total ~112 < the hard 128 cap rounds 7-10 established). Phases 10-11 in
// LDS (2 x 64 rows x 260-padded floats = 130KB, loaded ONCE in prologue --
// read-only afterwards, no DMA race class; stride 260 = 16B-aligned, 2-way
// quarter-conflicts = free per bank math). Phases 0-9 streamed as round 18
// (2-deep pipeline, mod-10 wrap). Step order: reg -> LDS -> streamed, so
// next-step prefetches land under the VALU-only phases. part indexing by
// absolute phase -> bit-identical numerics to round 18.
// Traffic: 640KB/step/CU -> streamed floor ~4.65us/step; VALU ~5us binds.
// 256 blocks x 1024 threads, 2 batch rows/block. 2 lgkm barriers/step.
// Reference semantics: cell_state c0 CONSTANT (enc[:,-1,:]); carry = c_new.
__global__ __launch_bounds__(1024) void rec_kernel(
    const float* __restrict__ enc,   // (512, 64, 256)
    const float* __restrict__ b_ih,  // (1024)
    const float* __restrict__ W_hh,  // (1024, 256)
    const float* __restrict__ b_hh,  // (1024)
    float* __restrict__ hstage)      // (512, 256, 256) staging (= d_out)
{
    const int tid  = threadIdx.x;
    const int wv   = tid >> 6;          // wave 0..15
    const int lane = tid & 63;
    const int kseg = lane & 7;          // 8 K-segments (interleaved chunks)
    const int r8   = lane >> 3;         // 0..7: row within wave's group
    const int half = wv >> 3;           // K-half
    const int wg   = wv & 7;            // row group
    const int rloc = 8*wg + r8;         // row-in-phase (0..63)
    const int b0   = blockIdx.x * 2;

    __shared__ __align__(16) float Wlds[2][64*260];  // phases 10,11: 133.1KB
    __shared__ float part[2][2][1024];               // 16KB
    __shared__ float h_lds[2][256];                  // 2KB  (total ~151KB)

    // ---- pointwise identity: threads 0..511 = (pj, ph) ----
    const int pj = tid & 255;
    const int ph = (tid >> 8) & 1;
    float c0 = 0.f, pb0 = 0.f, pb1 = 0.f, pb2 = 0.f, pb3 = 0.f;
    float* __restrict__ outp = nullptr;
    if (tid < 512) {
        c0  = enc[(size_t)(b0 + ph)*16384 + 16128 + pj];
        pb0 = b_ih[      pj] + b_hh[      pj];
        pb1 = b_ih[256 + pj] + b_hh[256 + pj];
        pb2 = b_ih[512 + pj] + b_hh[512 + pj];
        pb3 = b_ih[768 + pj] + b_hh[768 + pj];
        outp = hstage + (size_t)(b0 + ph)*65536 + pj;
    }

    // per-lane W base (interleaved: chunk i at +i*32 floats)
    const float* __restrict__ wbase =
        W_hh + (size_t)rloc*256 + half*128 + kseg*4;

    #define LOADP(q0, q1, q2, q3, pm) do {                           \
        const float* wp_ = wbase + (size_t)(pm)*16384;               \
        q0 = *(const f32x4*)(wp_     );                              \
        q1 = *(const f32x4*)(wp_ + 32);                              \
        q2 = *(const f32x4*)(wp_ + 64);                              \
        q3 = *(const f32x4*)(wp_ + 96);                              \
    } while (0)

    #define COMPUTE(q0, q1, q2, q3, p) do {                          \
        f32x4 s0 = q0*h00; f32x4 s1 = q0*h10;                        \
        s0 += q1*h01;      s1 += q1*h11;                             \
        s0 += q2*h02;      s1 += q2*h12;                             \
        s0 += q3*h03;      s1 += q3*h13;                             \
        float a0 = (s0.x + s0.y) + (s0.z + s0.w);                    \
        float a1 = (s1.x + s1.y) + (s1.z + s1.w);                    \
        a0 = red8(a0); a1 = red8(a1);                                \
        if (kseg == 0) {                                             \
            const int grow_ = (p)*64 + rloc;                         \
            part[half][0][grow_] = a0;                               \
            part[half][1][grow_] = a1;                               \
        }                                                            \
    } while (0)

    // LDS-resident phase: same body, operands from Wlds
    #define COMPUTE_L(li, p) do {                                    \
        const float* wl_ = &Wlds[li][rloc*260 + half*128 + kseg*4];  \
        const f32x4 t0 = *(const f32x4*)(wl_     );                  \
        const f32x4 t1 = *(const f32x4*)(wl_ + 32);                  \
        const f32x4 t2 = *(const f32x4*)(wl_ + 64);                  \
        const f32x4 t3 = *(const f32x4*)(wl_ + 96);                  \
        COMPUTE(t0, t1, t2, t3, p);                                  \
    } while (0)

    // h windows (interleaved chunks)
    f32x4 h00 = (f32x4)(0.f), h01 = (f32x4)(0.f),
          h02 = (f32x4)(0.f), h03 = (f32x4)(0.f);
    f32x4 h10 = (f32x4)(0.f), h11 = (f32x4)(0.f),
          h12 = (f32x4)(0.f), h13 = (f32x4)(0.f);

    // register-resident W: phases 12..15 (16 named f32x4 = 64 VGPR)
    f32x4 rA0, rA1, rA2, rA3, rB0, rB1, rB2, rB3;
    f32x4 rC0, rC1, rC2, rC3, rD0, rD1, rD2, rD3;
    LOADP(rA0, rA1, rA2, rA3, 12);
    LOADP(rB0, rB1, rB2, rB3, 13);
    LOADP(rC0, rC1, rC2, rC3, 14);
    LOADP(rD0, rD1, rD2, rD3, 15);

    // LDS preload of phases 10,11 (row-major, stride 260, 16B-aligned)
    for (int s = tid; s < 2*64*64; s += 1024) {
        const int li  = s >> 12;          // 0,1
        const int rem = s & 4095;
        const int row = rem >> 6;
        const int c4  = rem & 63;
        *(f32x4*)&Wlds[li][row*260 + c4*4] =
            *(const f32x4*)&W_hh[(size_t)(10 + li)*16384 + row*256 + c4*4];
    }

    // streamed pipeline (phases 0..9), primed with 0,1
    f32x4 wA0, wA1, wA2, wA3, wB0, wB1, wB2, wB3;
    LOADP(wA0, wA1, wA2, wA3, 0);
    LOADP(wB0, wB1, wB2, wB3, 1);

    __syncthreads();    // Wlds preload visible before first COMPUTE_L

    for (int t = 0; t < 256; ++t) {
        // --- resident phases first: pure VALU, hides in-flight prefetch ---
        COMPUTE(rA0, rA1, rA2, rA3, 12);
        COMPUTE(rB0, rB1, rB2, rB3, 13);
        COMPUTE(rC0, rC1, rC2, rC3, 14);
        COMPUTE(rD0, rD1, rD2, rD3, 15);
        COMPUTE_L(0, 10);
        COMPUTE_L(1, 11);
        // --- streamed phases 0..9, 2-deep pipeline, mod-10 wrap ---
        #pragma unroll 1
        for (int sp = 0; sp < 10; sp += 2) {
            int pm2 = sp + 2; if (pm2 >= 10) pm2 -= 10;   // wraps to next step
            int pm3 = sp + 3; if (pm3 >= 10) pm3 -= 10;   // (W const every step)
            COMPUTE(wA0, wA1, wA2, wA3, sp    );
            LOADP(wA0, wA1, wA2, wA3, pm2);
            COMPUTE(wB0, wB1, wB2, wB3, sp + 1);
            LOADP(wB0, wB1, wB2, wB3, pm3);
        }
        asm volatile("s_waitcnt lgkmcnt(0)" ::: "memory");
        __builtin_amdgcn_s_barrier();           // (1) all partials visible

        // ---- pointwise LSTM: threads 0..511, batch b0+ph, column pj ----
        if (tid < 512) {
            const float g0 = part[0][ph][      pj] + part[1][ph][      pj] + pb0;
            const float g1 = part[0][ph][256 + pj] + part[1][ph][256 + pj] + pb1;
            const float g2 = part[0][ph][512 + pj] + part[1][ph][512 + pj] + pb2;
            const float g3 = part[0][ph][768 + pj] + part[1][ph][768 + pj] + pb3;
            const float cn = sigm(g1)*c0 + sigm(g0)*tanhf(g2);
            const float hn = sigm(g3)*tanhf(cn);
            h_lds[ph][pj] = cn;                 // carry h_{t+1} = c_new
            __builtin_nontemporal_store(hn, outp + t*256);
        }
        asm volatile("s_waitcnt lgkmcnt(0)" ::: "memory");
        __builtin_amdgcn_s_barrier();           // (2) h ready

        // reload h windows (interleaved -> all 32 banks, conflict-free)
        h00 = *(const f32x4*)&h_lds[0][half*128 + kseg*4     ];
        h01 = *(const f32x4*)&h_lds[0][half*128 + kseg*4 + 32];
        h02 = *(const f32x4*)&h_lds[0][half*128 + kseg*4 + 64];
        h03 = *(const f32x4*)&h_lds[0][half*128 + kseg*4 + 96];
        h10 = *(const f32x4*)&h_lds[1][half*128 + kseg*4     ];
        h11 = *(const f32x4*)&h_lds[1][half*128 + kseg*4 + 32];
        h12 = *(const f32x4*)&h_lds[1][half*128 + kseg*4 + 64];
        h13 = *(const f32x4*)&h_lds[1][half*128 + kseg*4 + 96];
    }
    #undef LOADP
    #undef COMPUTE
    #undef COMPUTE_L
}

// ---------------- Kernel 2: logits + softmax, in place ----------------
// (unchanged — verified correct, ~106 us)
__global__ __launch_bounds__(1024) void out_kernel(
    const float* __restrict__ W2,    // (256, 256)
    const float* __restrict__ b2,    // (256)
    float* __restrict__ io)          // (131072, 256) h in, probs out
{
    const int tid = threadIdx.x;
    const int rg  = tid & 15;
    const int cg  = tid >> 4;        // 0..63
    const int m0  = blockIdx.x * 64;

    __shared__ float tile[64][260];

    #pragma unroll
    for (int i = 0; i < 4; ++i) {
        const int idx = tid + i*1024;     // 0..4095 float4 slots
        const int r   = idx >> 6;
        const int c4  = idx & 63;
        const f32x4 v = __builtin_nontemporal_load(
            (const f32x4*)(io + (size_t)(m0 + r)*256 + c4*4));
        *(f32x4*)&tile[r][c4*4] = v;
    }
    __syncthreads();

    float b2v[4];
    #pragma unroll
    for (int ci = 0; ci < 4; ++ci) b2v[ci] = b2[cg*4 + ci];

    float acc[4][4] = {};

    #pragma unroll 4
    for (int k4 = 0; k4 < 64; ++k4) {
        const f32x4 h0 = *(const f32x4*)&tile[rg     ][k4*4];
        const f32x4 h1 = *(const f32x4*)&tile[rg + 16][k4*4];
        const f32x4 h2 = *(const f32x4*)&tile[rg + 32][k4*4];
        const f32x4 h3 = *(const f32x4*)&tile[rg + 48][k4*4];
        #pragma unroll
        for (int ci = 0; ci < 4; ++ci) {
            const f32x4 wv = *(const f32x4*)(W2 + (size_t)(cg*4 + ci)*256 + k4*4);
            acc[0][ci] += wv.x*h0.x + wv.y*h0.y + wv.z*h0.z + wv.w*h0.w;
            acc[1][ci] += wv.x*h1.x + wv.y*h1.y + wv.z*h1.z + wv.w*h1.w;
            acc[2][ci] += wv.x*h2.x + wv.y*h2.y + wv.z*h2.z + wv.w*h2.w;
            acc[3][ci] += wv.x*h3.x + wv.y*h3.y + wv.z*h3.z + wv.w*h3.w;
        }
    }
    __syncthreads();

    #pragma unroll
    for (int ri = 0; ri < 4; ++ri) {
        f32x4 v;
        v.x = acc[ri][0] + b2v[0];
        v.y = acc[ri][1] + b2v[1];
        v.z = acc[ri][2] + b2v[2];
        v.w = acc[ri][3] + b2v[3];
        *(f32x4*)&tile[rg + 16*ri][cg*4] = v;
    }
    __syncthreads();

    const int wv_ = tid >> 6;
    const int l   = tid & 63;
    #pragma unroll
    for (int rr2 = 0; rr2 < 4; ++rr2) {
        const int r = wv_*4 + rr2;
        const float v0 = tile[r][l      ];
        const float v1 = tile[r][l +  64];
        const float v2 = tile[r][l + 128];
        const float v3 = tile[r][l + 192];
        float m = fmaxf(fmaxf(v0, v1), fmaxf(v2, v3));
        #pragma unroll
        for (int off = 32; off > 0; off >>= 1)
            m = fmaxf(m, __shfl_xor(m, off));
        const float e0 = expf(v0 - m), e1 = expf(v1 - m);
        const float e2 = expf(v2 - m), e3 = expf(v3 - m);
        float s = e0 + e1 + e2 + e3;
        #pragma unroll
        for (int off = 32; off > 0; off >>= 1)
            s += __shfl_xor(s, off);
        const float inv = 1.0f / s;
        float* op = io + (size_t)(m0 + r)*256;
        __builtin_nontemporal_store(e0*inv, op + l      );
        __builtin_nontemporal_store(e1*inv, op + l +  64);
        __builtin_nontemporal_store(e2*inv, op + l + 128);
        __builtin_nontemporal_store(e3*inv, op + l + 192);
    }
}

extern "C" void kernel_launch(void* const* d_in, const int* in_sizes, int n_in,
                              void* d_out, int out_size, void* d_ws, size_t ws_size,
                              hipStream_t stream) {
    // inputs: input, encoder_output, W_ih, b_ih, W_hh, b_hh, W2, b2
    // (input and W_ih are mathematically unused: x_part = 0 @ W_ih.T + b_ih)
    const float* enc  = (const float*)d_in[1];
    const float* b_ih = (const float*)d_in[3];
    const float* W_hh = (const float*)d_in[4];
    const float* b_hh = (const float*)d_in[5];
    const float* W2   = (const float*)d_in[6];
    const float* b2   = (const float*)d_in[7];
    float* outp = (float*)d_out;

    hipLaunchKernelGGL(rec_kernel, dim3(256), dim3(1024), 0, stream,
                       enc, b_ih, W_hh, b_hh, outp);
    hipLaunchKernelGGL(out_kernel, dim3(2048), dim3(1024), 0, stream,
                       W2, b2, outp);
}

// Round 20
// 2409.777 us; speedup vs baseline: 1.5743x; 1.5743x over previous
//
#include <hip/hip_runtime.h>
#include <math.h>
#include <stdint.h>

typedef float f32x4 __attribute__((ext_vector_type(4)));

__device__ __forceinline__ float sigm(float x) { return 1.0f/(1.0f+expf(-x)); }

// Sum across each 8-lane group via DIRECTION-PROOF DPP involutions (round-16
// lesson: ror over sub-groups is direction-sensitive; xor/mirror are not).
__device__ __forceinline__ float red8(float v) {
    int t;
    t = __builtin_amdgcn_update_dpp(0, __float_as_int(v), 0xB1, 0xf, 0xf, false);
    v += __int_as_float(t);   // + lane^1
    t = __builtin_amdgcn_update_dpp(0, __float_as_int(v), 0x4E, 0xf, 0xf, false);
    v += __int_as_float(t);   // + lane^2 -> quad sums
    t = __builtin_amdgcn_update_dpp(0, __float_as_int(v), 0x141, 0xf, 0xf, false);
    v += __int_as_float(t);   // + row_half_mirror -> 8-sum in all lanes
    return v;
}

// ------------- Kernel 1: LSTM recurrence, LDS-partially-resident W -------------
// Round-19 forensics: (a) register-resident W spilled at the 1024-thread
// 64-VGPR allocator cap -> 5.7GB scratch HBM -> 3.8ms; (b) the 6.7e7 LDS
// "conflicts" were EXACTLY inherent b128 accounting (8 bank-accesses per
// wave64 ds_read_b128: 16wv x 2ph x 4rd x 256st x 256CU x 8 = 6.7e7), not a
// layout bug. Therefore: keep LDS residency, drop register residency.
// This round = round-18 base (PASSED, 2.72ms rec, 48 VGPR) + phases 14,15
// resident in LDS (2 x 64 x 260-padded = 133KB, preloaded ONCE, read-only ->
// no DMA-race class; stride 260 spreads 4-aligned starts evenly over banks).
// Phases 0..13 streamed exactly as round 18 (2-deep pipeline, mod-14 wrap).
// LDS phases run FIRST each step so wrapped prefetches land under VALU work.
// Traffic: 1MiB -> 896KB/step/CU (L1 floor 6.8 -> 5.95us; L2 agg 7.4 -> 6.5).
// part indexed by absolute phase -> bit-identical numerics to round 18.
// 256 blocks x 1024 threads, 2 batch rows/block. 2 lgkm barriers/step.
// Reference semantics: cell_state c0 CONSTANT (enc[:,-1,:]); carry = c_new.
__global__ __launch_bounds__(1024) void rec_kernel(
    const float* __restrict__ enc,   // (512, 64, 256)
    const float* __restrict__ b_ih,  // (1024)
    const float* __restrict__ W_hh,  // (1024, 256)
    const float* __restrict__ b_hh,  // (1024)
    float* __restrict__ hstage)      // (512, 256, 256) staging (= d_out)
{
    const int tid  = threadIdx.x;
    const int wv   = tid >> 6;          // wave 0..15
    const int lane = tid & 63;
    const int kseg = lane & 7;          // 8 K-segments (interleaved chunks)
    const int r8   = lane >> 3;         // 0..7: row within wave's group
    const int half = wv >> 3;           // K-half
    const int wg   = wv & 7;            // row group
    const int rloc = 8*wg + r8;         // row-in-phase (0..63)
    const int b0   = blockIdx.x * 2;

    __shared__ __align__(16) float Wlds[2][64*260];  // phases 14,15: 133.1KB
    __shared__ float part[2][2][1024];               // 16KB
    __shared__ float h_lds[2][256];                  // 2KB  (total ~151KB)

    // ---- pointwise identity: threads 0..511 = (pj, ph) ----
    const int pj = tid & 255;
    const int ph = (tid >> 8) & 1;
    float c0 = 0.f, pb0 = 0.f, pb1 = 0.f, pb2 = 0.f, pb3 = 0.f;
    float* __restrict__ outp = nullptr;
    if (tid < 512) {
        c0  = enc[(size_t)(b0 + ph)*16384 + 16128 + pj];
        pb0 = b_ih[      pj] + b_hh[      pj];
        pb1 = b_ih[256 + pj] + b_hh[256 + pj];
        pb2 = b_ih[512 + pj] + b_hh[512 + pj];
        pb3 = b_ih[768 + pj] + b_hh[768 + pj];
        outp = hstage + (size_t)(b0 + ph)*65536 + pj;
    }

    // per-lane W base (interleaved: chunk i at +i*32 floats)
    const float* __restrict__ wbase =
        W_hh + (size_t)rloc*256 + half*128 + kseg*4;

    #define LOADP(q0, q1, q2, q3, pm) do {                           \
        const float* wp_ = wbase + (size_t)(pm)*16384;               \
        q0 = *(const f32x4*)(wp_     );                              \
        q1 = *(const f32x4*)(wp_ + 32);                              \
        q2 = *(const f32x4*)(wp_ + 64);                              \
        q3 = *(const f32x4*)(wp_ + 96);                              \
    } while (0)

    #define COMPUTE(q0, q1, q2, q3, p) do {                          \
        f32x4 s0 = q0*h00; f32x4 s1 = q0*h10;                        \
        s0 += q1*h01;      s1 += q1*h11;                             \
        s0 += q2*h02;      s1 += q2*h12;                             \
        s0 += q3*h03;      s1 += q3*h13;                             \
        float a0 = (s0.x + s0.y) + (s0.z + s0.w);                    \
        float a1 = (s1.x + s1.y) + (s1.z + s1.w);                    \
        a0 = red8(a0); a1 = red8(a1);                                \
        if (kseg == 0) {                                             \
            const int grow_ = (p)*64 + rloc;                         \
            part[half][0][grow_] = a0;                               \
            part[half][1][grow_] = a1;                               \
        }                                                            \
    } while (0)

    // LDS-resident phase: same body, operands from Wlds (transients only)
    #define COMPUTE_L(li, p) do {                                    \
        const float* wl_ = &Wlds[li][rloc*260 + half*128 + kseg*4];  \
        const f32x4 t0 = *(const f32x4*)(wl_     );                  \
        const f32x4 t1 = *(const f32x4*)(wl_ + 32);                  \
        const f32x4 t2 = *(const f32x4*)(wl_ + 64);                  \
        const f32x4 t3 = *(const f32x4*)(wl_ + 96);                  \
        COMPUTE(t0, t1, t2, t3, p);                                  \
    } while (0)

    // h windows (interleaved chunks)
    f32x4 h00 = (f32x4)(0.f), h01 = (f32x4)(0.f),
          h02 = (f32x4)(0.f), h03 = (f32x4)(0.f);
    f32x4 h10 = (f32x4)(0.f), h11 = (f32x4)(0.f),
          h12 = (f32x4)(0.f), h13 = (f32x4)(0.f);

    // LDS preload of phases 14,15 (row-major, stride 260, 16B-aligned)
    for (int s = tid; s < 2*64*64; s += 1024) {
        const int li  = s >> 12;          // 0,1
        const int rem = s & 4095;
        const int row = rem >> 6;
        const int c4  = rem & 63;
        *(f32x4*)&Wlds[li][row*260 + c4*4] =
            *(const f32x4*)&W_hh[(size_t)(14 + li)*16384 + row*256 + c4*4];
    }

    // streamed pipeline (phases 0..13), primed with 0,1
    f32x4 wA0, wA1, wA2, wA3, wB0, wB1, wB2, wB3;
    LOADP(wA0, wA1, wA2, wA3, 0);
    LOADP(wB0, wB1, wB2, wB3, 1);

    __syncthreads();    // Wlds preload visible before first COMPUTE_L

    for (int t = 0; t < 256; ++t) {
        // --- LDS-resident phases first: no L1 traffic, prefetch lands ---
        COMPUTE_L(0, 14);
        COMPUTE_L(1, 15);
        // --- streamed phases 0..13, 2-deep pipeline, mod-14 wrap ---
        #pragma unroll 1
        for (int sp = 0; sp < 14; sp += 2) {
            int pm2 = sp + 2; if (pm2 >= 14) pm2 -= 14;   // wraps to next step
            int pm3 = sp + 3; if (pm3 >= 14) pm3 -= 14;   // (W const every step)
            COMPUTE(wA0, wA1, wA2, wA3, sp    );
            LOADP(wA0, wA1, wA2, wA3, pm2);
            COMPUTE(wB0, wB1, wB2, wB3, sp + 1);
            LOADP(wB0, wB1, wB2, wB3, pm3);
        }
        asm volatile("s_waitcnt lgkmcnt(0)" ::: "memory");
        __builtin_amdgcn_s_barrier();           // (1) all partials visible

        // ---- pointwise LSTM: threads 0..511, batch b0+ph, column pj ----
        if (tid < 512) {
            const float g0 = part[0][ph][      pj] + part[1][ph][      pj] + pb0;
            const float g1 = part[0][ph][256 + pj] + part[1][ph][256 + pj] + pb1;
            const float g2 = part[0][ph][512 + pj] + part[1][ph][512 + pj] + pb2;
            const float g3 = part[0][ph][768 + pj] + part[1][ph][768 + pj] + pb3;
            const float cn = sigm(g1)*c0 + sigm(g0)*tanhf(g2);
            const float hn = sigm(g3)*tanhf(cn);
            h_lds[ph][pj] = cn;                 // carry h_{t+1} = c_new
            __builtin_nontemporal_store(hn, outp + t*256);
        }
        asm volatile("s_waitcnt lgkmcnt(0)" ::: "memory");
        __builtin_amdgcn_s_barrier();           // (2) h ready

        // reload h windows (interleaved -> all 32 banks, conflict-free)
        h00 = *(const f32x4*)&h_lds[0][half*128 + kseg*4     ];
        h01 = *(const f32x4*)&h_lds[0][half*128 + kseg*4 + 32];
        h02 = *(const f32x4*)&h_lds[0][half*128 + kseg*4 + 64];
        h03 = *(const f32x4*)&h_lds[0][half*128 + kseg*4 + 96];
        h10 = *(const f32x4*)&h_lds[1][half*128 + kseg*4     ];
        h11 = *(const f32x4*)&h_lds[1][half*128 + kseg*4 + 32];
        h12 = *(const f32x4*)&h_lds[1][half*128 + kseg*4 + 64];
        h13 = *(const f32x4*)&h_lds[1][half*128 + kseg*4 + 96];
    }
    #undef LOADP
    #undef COMPUTE
    #undef COMPUTE_L
}

// ---------------- Kernel 2: logits + softmax, in place ----------------
// (unchanged — verified correct, ~106 us)
__global__ __launch_bounds__(1024) void out_kernel(
    const float* __restrict__ W2,    // (256, 256)
    const float* __restrict__ b2,    // (256)
    float* __restrict__ io)          // (131072, 256) h in, probs out
{
    const int tid = threadIdx.x;
    const int rg  = tid & 15;
    const int cg  = tid >> 4;        // 0..63
    const int m0  = blockIdx.x * 64;

    __shared__ float tile[64][260];

    #pragma unroll
    for (int i = 0; i < 4; ++i) {
        const int idx = tid + i*1024;     // 0..4095 float4 slots
        const int r   = idx >> 6;
        const int c4  = idx & 63;
        const f32x4 v = __builtin_nontemporal_load(
            (const f32x4*)(io + (size_t)(m0 + r)*256 + c4*4));
        *(f32x4*)&tile[r][c4*4] = v;
    }
    __syncthreads();

    float b2v[4];
    #pragma unroll
    for (int ci = 0; ci < 4; ++ci) b2v[ci] = b2[cg*4 + ci];

    float acc[4][4] = {};

    #pragma unroll 4
    for (int k4 = 0; k4 < 64; ++k4) {
        const f32x4 h0 = *(const f32x4*)&tile[rg     ][k4*4];
        const f32x4 h1 = *(const f32x4*)&tile[rg + 16][k4*4];
        const f32x4 h2 = *(const f32x4*)&tile[rg + 32][k4*4];
        const f32x4 h3 = *(const f32x4*)&tile[rg + 48][k4*4];
        #pragma unroll
        for (int ci = 0; ci < 4; ++ci) {
            const f32x4 wv = *(const f32x4*)(W2 + (size_t)(cg*4 + ci)*256 + k4*4);
            acc[0][ci] += wv.x*h0.x + wv.y*h0.y + wv.z*h0.z + wv.w*h0.w;
            acc[1][ci] += wv.x*h1.x + wv.y*h1.y + wv.z*h1.z + wv.w*h1.w;
            acc[2][ci] += wv.x*h2.x + wv.y*h2.y + wv.z*h2.z + wv.w*h2.w;
            acc[3][ci] += wv.x*h3.x + wv.y*h3.y + wv.z*h3.z + wv.w*h3.w;
        }
    }
    __syncthreads();

    #pragma unroll
    for (int ri = 0; ri < 4; ++ri) {
        f32x4 v;
        v.x = acc[ri][0] + b2v[0];
        v.y = acc[ri][1] + b2v[1];
        v.z = acc[ri][2] + b2v[2];
        v.w = acc[ri][3] + b2v[3];
        *(f32x4*)&tile[rg + 16*ri][cg*4] = v;
    }
    __syncthreads();

    const int wv_ = tid >> 6;
    const int l   = tid & 63;
    #pragma unroll
    for (int rr2 = 0; rr2 < 4; ++rr2) {
        const int r = wv_*4 + rr2;
        const float v0 = tile[r][l      ];
        const float v1 = tile[r][l +  64];
        const float v2 = tile[r][l + 128];
        const float v3 = tile[r][l + 192];
        float m = fmaxf(fmaxf(v0, v1), fmaxf(v2, v3));
        #pragma unroll
        for (int off = 32; off > 0; off >>= 1)
            m = fmaxf(m, __shfl_xor(m, off));
        const float e0 = expf(v0 - m), e1 = expf(v1 - m);
        const float e2 = expf(v2 - m), e3 = expf(v3 - m);
        float s = e0 + e1 + e2 + e3;
        #pragma unroll
        for (int off = 32; off > 0; off >>= 1)
            s += __shfl_xor(s, off);
        const float inv = 1.0f / s;
        float* op = io + (size_t)(m0 + r)*256;
        __builtin_nontemporal_store(e0*inv, op + l      );
        __builtin_nontemporal_store(e1*inv, op + l +  64);
        __builtin_nontemporal_store(e2*inv, op + l + 128);
        __builtin_nontemporal_store(e3*inv, op + l + 192);
    }
}

extern "C" void kernel_launch(void* const* d_in, const int* in_sizes, int n_in,
                              void* d_out, int out_size, void* d_ws, size_t ws_size,
                              hipStream_t stream) {
    // inputs: input, encoder_output, W_ih, b_ih, W_hh, b_hh, W2, b2
    // (input and W_ih are mathematically unused: x_part = 0 @ W_ih.T + b_ih)
    const float* enc  = (const float*)d_in[1];
    const float* b_ih = (const float*)d_in[3];
    const float* W_hh = (const float*)d_in[4];
    const float* b_hh = (const float*)d_in[5];
    const float* W2   = (const float*)d_in[6];
    const float* b2   = (const float*)d_in[7];
    float* outp = (float*)d_out;

    hipLaunchKernelGGL(rec_kernel, dim3(256), dim3(1024), 0, stream,
                       enc, b_ih, W_hh, b_hh, outp);
    hipLaunchKernelGGL(out_kernel, dim3(2048), dim3(1024), 0, stream,
                       W2, b2, outp);
}